// Round 8
// baseline (334.871 us; speedup 1.0000x reference)
//
#include <hip/hip_runtime.h>
#include <hip/hip_fp16.h>

// ---------------------------------------------------------------------------
// GIN, round 8: round-7 + degree-sorted node permutation.
// Waves process nodes in degree-sorted order (perm built from a 64-bucket
// counting sort; histogram folded into k_build). Eliminates degree
// divergence in the gather loops (E[max of 32 Poisson(16)] ~ 26 vs mean 16).
// Per-node math and edge order unchanged -> output bit-identical.
// ---------------------------------------------------------------------------

typedef unsigned int uint_t;

#define NBLK 256
#define NBMAX 400

struct alignas(16) H2x4 { __half2 x, y, z, w; };  // 8 f16 channels

static __device__ __forceinline__ float selu_f(float x) {
    const float scale = 1.0507009873554805f;
    const float alpha = 1.6732632423543772f;
    return x > 0.f ? scale * x : scale * alpha * (__expf(x) - 1.f);
}

// quad_perm DPP helpers (pairs stay inside quads)
static __device__ __forceinline__ int pb0(int v) {   // lanes {0,1}<-0, {2,3}<-2
    return __builtin_amdgcn_mov_dpp(v, 0xA0, 0xf, 0xf, true);
}
static __device__ __forceinline__ int pb1(int v) {   // lanes {0,1}<-1, {2,3}<-3
    return __builtin_amdgcn_mov_dpp(v, 0xF5, 0xf, 0xf, true);
}
static __device__ __forceinline__ float pswap(float x) {  // pair swap [1,0,3,2]
    return __int_as_float(__builtin_amdgcn_mov_dpp(__float_as_int(x), 0xB1, 0xf, 0xf, true));
}

static __device__ __forceinline__ void acc_add(__half2& a0, __half2& a1,
                                               __half2& a2, __half2& a3, H2x4 v) {
    a0 = __hadd2(a0, v.x); a1 = __hadd2(a1, v.y);
    a2 = __hadd2(a2, v.z); a3 = __hadd2(a3, v.w);
}

// ============================ CSR build =====================================

__global__ void k_hist(const int* __restrict__ dst, int* __restrict__ MT,
                       int e, int nb) {
    __shared__ int hist[NBMAX];
    for (int t = threadIdx.x; t < nb; t += 256) hist[t] = 0;
    __syncthreads();
    int chunk = (e + NBLK - 1) / NBLK;
    int lo = blockIdx.x * chunk, hi = min(e, lo + chunk);
    for (int i = lo + threadIdx.x; i < hi; i += 256)
        atomicAdd(&hist[dst[i] >> 8], 1);
    __syncthreads();
    for (int t = threadIdx.x; t < nb; t += 256)
        MT[t * NBLK + blockIdx.x] = hist[t];
}

__global__ void k_cscan(int* __restrict__ MT, int* __restrict__ tot, int nb) {
    int k = blockIdx.x;
    int lane = threadIdx.x;  // 64
    int carry = 0;
    #pragma unroll
    for (int r = 0; r < NBLK; r += 64) {
        int v = MT[k * NBLK + r + lane];
        int inc = v;
        #pragma unroll
        for (int d = 1; d < 64; d <<= 1) {
            int w = __shfl_up(inc, d, 64);
            if (lane >= d) inc += w;
        }
        MT[k * NBLK + r + lane] = carry + inc - v;
        carry += __shfl(inc, 63, 64);
    }
    if (lane == 0) tot[k] = carry;
}

__global__ void k_bscan(const int* __restrict__ tot, int* __restrict__ base,
                        int* __restrict__ rp, int nb, int e, int n) {
    __shared__ int s[512];
    int t = threadIdx.x;
    int v = (t < nb) ? tot[t] : 0;
    s[t] = v;
    __syncthreads();
    #pragma unroll
    for (int d = 1; d < 512; d <<= 1) {
        int w = (t >= d) ? s[t - d] : 0;
        __syncthreads();
        s[t] += w;
        __syncthreads();
    }
    if (t < nb) base[t] = s[t] - v;
    if (t == nb - 1) base[nb] = s[t];
    if (t == 0) rp[n] = e;
}

__global__ void k_scatter(const int* __restrict__ src, const int* __restrict__ dst,
                          const int* __restrict__ MT, const int* __restrict__ base,
                          uint_t* __restrict__ pairs, int e, int nb) {
    __shared__ int cur[NBMAX];
    for (int t = threadIdx.x; t < nb; t += 256)
        cur[t] = base[t] + MT[t * NBLK + blockIdx.x];
    __syncthreads();
    int chunk = (e + NBLK - 1) / NBLK;
    int lo = blockIdx.x * chunk, hi = min(e, lo + chunk);
    for (int i = lo + threadIdx.x; i < hi; i += 256) {
        int d = dst[i];
        int pos = atomicAdd(&cur[d >> 8], 1);
        pairs[pos] = (uint_t)src[i] | ((uint_t)(d & 255) << 24);
    }
}

// builds rp + esrc for its 256 nodes; also accumulates the global degree
// histogram (64 buckets, clamped) used for the degree-sort permutation.
__global__ void k_build(const uint_t* __restrict__ pairs, const int* __restrict__ base,
                        int* __restrict__ rp, int* __restrict__ esrc,
                        int* __restrict__ DH2, int n) {
    int k = blockIdx.x;
    int bb = base[k], be = base[k + 1];
    __shared__ int cnt[256], cur[256], stmp[256], dh[64];
    int t = threadIdx.x;
    cnt[t] = 0;
    if (t < 64) dh[t] = 0;
    __syncthreads();
    for (int i = bb + t; i < be; i += 256)
        atomicAdd(&cnt[pairs[i] >> 24], 1);
    __syncthreads();
    int v = cnt[t];
    int nd = k * 256 + t;
    if (nd < n) atomicAdd(&dh[min(v, 63)], 1);
    stmp[t] = v;
    __syncthreads();
    #pragma unroll
    for (int d = 1; d < 256; d <<= 1) {
        int w = (t >= d) ? stmp[t - d] : 0;
        __syncthreads();
        stmp[t] += w;
        __syncthreads();
    }
    int excl = stmp[t] - v;
    if (nd < n) rp[nd] = bb + excl;
    cur[t] = bb + excl;
    if (t < 64 && dh[t] > 0) atomicAdd(&DH2[t], dh[t]);
    __syncthreads();
    for (int i = bb + t; i < be; i += 256) {
        uint_t p = pairs[i];
        int pos = atomicAdd(&cur[p >> 24], 1);
        esrc[pos] = (int)(p & 0xFFFFFFu);
    }
}

// exclusive scan of the 64-bucket degree histogram -> global cursors
__global__ void k_dbase(const int* __restrict__ DH2, int* __restrict__ gcur) {
    int lane = threadIdx.x;  // 64
    int v = DH2[lane];
    int inc = v;
    #pragma unroll
    for (int d = 1; d < 64; d <<= 1) {
        int w = __shfl_up(inc, d, 64);
        if (lane >= d) inc += w;
    }
    gcur[lane] = inc - v;
}

// scatter node ids into degree-sorted perm (order within bucket arbitrary —
// does not affect any per-node arithmetic, output is bit-identical)
__global__ void k_dscatter(const int* __restrict__ rp, int* __restrict__ gcur,
                           int* __restrict__ perm, int n) {
    __shared__ int hist[64], bbase[64], cur2[64];
    int t = threadIdx.x;
    if (t < 64) hist[t] = 0;
    __syncthreads();
    int nd = blockIdx.x * 256 + t;
    int bucket = 0;
    if (nd < n) {
        int deg = rp[nd + 1] - rp[nd];
        bucket = min(deg, 63);
        atomicAdd(&hist[bucket], 1);
    }
    __syncthreads();
    if (t < 64 && hist[t] > 0) bbase[t] = atomicAdd(&gcur[t], hist[t]);
    __syncthreads();
    if (t < 64) cur2[t] = (hist[t] > 0) ? bbase[t] : 0;
    __syncthreads();
    if (nd < n) {
        int pos = atomicAdd(&cur2[bucket], 1);
        perm[pos] = nd;
    }
}

// ============================ network kernels ===============================

// block 0: agg(x) + MLP[1,16,32] -> h1 AND g1 = h1 @ W1next. One thread/node.
__global__ void k_b0g(const float* __restrict__ x, const int* __restrict__ rp,
                      const int* __restrict__ esrc, const int* __restrict__ perm,
                      const float* __restrict__ W1, const float* __restrict__ b1,
                      const float* __restrict__ W2, const float* __restrict__ b2,
                      const float* __restrict__ W1next,
                      __half2* __restrict__ hout, __half2* __restrict__ gout, int n) {
    __shared__ float sW1[16], sb1[16], sW2[512], sb2[32], sWn[512];
    if (threadIdx.x < 16) { sW1[threadIdx.x] = W1[threadIdx.x]; sb1[threadIdx.x] = b1[threadIdx.x]; }
    for (int t = threadIdx.x; t < 512; t += 256) { sW2[t] = W2[t]; sWn[t] = W1next[t]; }
    if (threadIdx.x < 32) sb2[threadIdx.x] = b2[threadIdx.x];
    __syncthreads();
    int idx = blockIdx.x * blockDim.x + threadIdx.x;
    if (idx >= n) return;
    const int i = perm[idx];
    float a = x[i];
    int b = rp[i], en = rp[i + 1];
    int j = b;
    for (; j + 4 <= en; j += 4) {
        int s0 = esrc[j], s1 = esrc[j + 1], s2 = esrc[j + 2], s3 = esrc[j + 3];
        float x0 = x[s0], x1 = x[s1], x2 = x[s2], x3 = x[s3];
        a += (x0 + x1) + (x2 + x3);
    }
    for (; j < en; ++j) a += x[esrc[j]];
    float u[16];
    #pragma unroll
    for (int k = 0; k < 16; ++k) u[k] = selu_f(fmaf(a, sW1[k], sb1[k]));
    float row[32];
    #pragma unroll
    for (int jj = 0; jj < 32; ++jj) {
        float acc = sb2[jj];
        #pragma unroll
        for (int k = 0; k < 16; ++k) acc = fmaf(u[k], sW2[k * 32 + jj], acc);
        row[jj] = acc;
    }
    H2x4* op = (H2x4*)hout + i * 4;
    #pragma unroll
    for (int q = 0; q < 4; ++q) {
        H2x4 vv;
        vv.x = __floats2half2_rn(row[q * 8 + 0], row[q * 8 + 1]);
        vv.y = __floats2half2_rn(row[q * 8 + 2], row[q * 8 + 3]);
        vv.z = __floats2half2_rn(row[q * 8 + 4], row[q * 8 + 5]);
        vv.w = __floats2half2_rn(row[q * 8 + 6], row[q * 8 + 7]);
        op[q] = vv;
    }
    float g[16];
    #pragma unroll
    for (int k = 0; k < 16; ++k) g[k] = 0.f;
    #pragma unroll
    for (int c = 0; c < 32; ++c) {
        float vc = row[c];
        #pragma unroll
        for (int k = 0; k < 16; ++k) g[k] = fmaf(vc, sWn[c * 16 + k], g[k]);
    }
    H2x4* gp = (H2x4*)gout + i * 2;
    #pragma unroll
    for (int q = 0; q < 2; ++q) {
        H2x4 vv;
        vv.x = __floats2half2_rn(g[q * 8 + 0], g[q * 8 + 1]);
        vv.y = __floats2half2_rn(g[q * 8 + 2], g[q * 8 + 3]);
        vv.z = __floats2half2_rn(g[q * 8 + 4], g[q * 8 + 5]);
        vv.w = __floats2half2_rn(g[q * 8 + 6], g[q * 8 + 7]);
        gp[q] = vv;
    }
}

// mid gather + MLP + residual + fused next-projection. Degree-sorted nodes.
template<int MODE>
__global__ __launch_bounds__(256, 4) void k_gmid(
    const __half2* __restrict__ gin, const __half2* __restrict__ hin,
    const int* __restrict__ rp, const int* __restrict__ esrc,
    const int* __restrict__ perm,
    const float* __restrict__ W2, const float* __restrict__ b1,
    const float* __restrict__ b2, const float* __restrict__ Wnext,
    __half2* __restrict__ hout, __half2* __restrict__ gout,
    float* __restrict__ zout, int n) {
    __shared__ float sW2[512], sb1[16], sb2[32];
    __shared__ float sWn[512];
    for (int t = threadIdx.x; t < 512; t += 256) sW2[t] = W2[t];
    if (MODE == 0) {
        for (int t = threadIdx.x; t < 512; t += 256) sWn[t] = Wnext[t];
    } else {
        if (threadIdx.x < 32) sWn[threadIdx.x] = Wnext[threadIdx.x];
    }
    if (threadIdx.x < 16) sb1[threadIdx.x] = b1[threadIdx.x];
    else if (threadIdx.x < 48) sb2[threadIdx.x - 16] = b2[threadIdx.x - 16];
    __syncthreads();

    const int lane2 = threadIdx.x & 1;
    const int idx = blockIdx.x * 128 + (threadIdx.x >> 1);
    if (idx >= n) return;
    const int node = perm[idx];

    const H2x4* grows = (const H2x4*)gin;
    H2x4 a = grows[node * 2 + lane2];
    __half2 a0 = a.x, a1 = a.y, a2 = a.z, a3 = a.w;

    int b = rp[node];
    int deg = rp[node + 1] - b;
    int j0 = 0;
    for (; j0 + 8 <= deg; j0 += 8) {
        int e0 = esrc[b + j0 + lane2];
        int e1 = esrc[b + j0 + 2 + lane2];
        int e2 = esrc[b + j0 + 4 + lane2];
        int e3 = esrc[b + j0 + 6 + lane2];
        int s0 = pb0(e0), s1 = pb1(e0), s2 = pb0(e1), s3 = pb1(e1);
        int s4 = pb0(e2), s5 = pb1(e2), s6 = pb0(e3), s7 = pb1(e3);
        H2x4 v0 = grows[s0 * 2 + lane2];
        H2x4 v1 = grows[s1 * 2 + lane2];
        H2x4 v2 = grows[s2 * 2 + lane2];
        H2x4 v3 = grows[s3 * 2 + lane2];
        H2x4 v4 = grows[s4 * 2 + lane2];
        H2x4 v5 = grows[s5 * 2 + lane2];
        H2x4 v6 = grows[s6 * 2 + lane2];
        H2x4 v7 = grows[s7 * 2 + lane2];
        acc_add(a0, a1, a2, a3, v0);
        acc_add(a0, a1, a2, a3, v1);
        acc_add(a0, a1, a2, a3, v2);
        acc_add(a0, a1, a2, a3, v3);
        acc_add(a0, a1, a2, a3, v4);
        acc_add(a0, a1, a2, a3, v5);
        acc_add(a0, a1, a2, a3, v6);
        acc_add(a0, a1, a2, a3, v7);
    }
    for (; j0 < deg; ++j0) {
        int s = esrc[b + j0];
        H2x4 v = grows[s * 2 + lane2];
        acc_add(a0, a1, a2, a3, v);
    }

    float2 f0 = __half22float2(a0), f1 = __half22float2(a1),
           f2 = __half22float2(a2), f3 = __half22float2(a3);
    float u[8] = {f0.x, f0.y, f1.x, f1.y, f2.x, f2.y, f3.x, f3.y};
    const int kb = lane2 * 8;
    #pragma unroll
    for (int q = 0; q < 8; ++q) u[q] = selu_f(u[q] + sb1[kb + q]);

    float ua[16];
    #pragma unroll
    for (int q = 0; q < 8; ++q) {
        float uo = pswap(u[q]);
        ua[q]     = lane2 ? uo   : u[q];
        ua[8 + q] = lane2 ? u[q] : uo;
    }

    const H2x4* hrows = (const H2x4*)hin;
    H2x4 h0 = hrows[node * 4 + lane2 * 2];
    H2x4 h1 = hrows[node * 4 + lane2 * 2 + 1];
    float hv[16];
    {
        float2 g0 = __half22float2(h0.x), g1 = __half22float2(h0.y),
               g2 = __half22float2(h0.z), g3 = __half22float2(h0.w);
        float2 g4 = __half22float2(h1.x), g5 = __half22float2(h1.y),
               g6 = __half22float2(h1.z), g7 = __half22float2(h1.w);
        hv[0] = g0.x; hv[1] = g0.y; hv[2] = g1.x; hv[3] = g1.y;
        hv[4] = g2.x; hv[5] = g2.y; hv[6] = g3.x; hv[7] = g3.y;
        hv[8] = g4.x; hv[9] = g4.y; hv[10] = g5.x; hv[11] = g5.y;
        hv[12] = g6.x; hv[13] = g6.y; hv[14] = g7.x; hv[15] = g7.y;
    }

    const int jb = lane2 * 16;
    float o[16];
    #pragma unroll
    for (int q = 0; q < 16; ++q) {
        float oo = sb2[jb + q];
        #pragma unroll
        for (int k = 0; k < 16; ++k) oo = fmaf(ua[k], sW2[k * 32 + jb + q], oo);
        o[q] = oo + hv[q];
    }

    if (MODE == 0) {
        H2x4 o0, o1;
        o0.x = __floats2half2_rn(o[0], o[1]);   o0.y = __floats2half2_rn(o[2], o[3]);
        o0.z = __floats2half2_rn(o[4], o[5]);   o0.w = __floats2half2_rn(o[6], o[7]);
        o1.x = __floats2half2_rn(o[8], o[9]);   o1.y = __floats2half2_rn(o[10], o[11]);
        o1.z = __floats2half2_rn(o[12], o[13]); o1.w = __floats2half2_rn(o[14], o[15]);
        ((H2x4*)hout)[node * 4 + lane2 * 2]     = o0;
        ((H2x4*)hout)[node * 4 + lane2 * 2 + 1] = o1;
        float gp[16];
        #pragma unroll
        for (int k = 0; k < 16; ++k) gp[k] = 0.f;
        #pragma unroll
        for (int q = 0; q < 16; ++q) {
            float vc = o[q];
            #pragma unroll
            for (int k = 0; k < 16; ++k)
                gp[k] = fmaf(vc, sWn[(jb + q) * 16 + k], gp[k]);
        }
        #pragma unroll
        for (int k = 0; k < 16; ++k) gp[k] += pswap(gp[k]);
        H2x4 gv;
        gv.x = __floats2half2_rn(gp[kb + 0], gp[kb + 1]);
        gv.y = __floats2half2_rn(gp[kb + 2], gp[kb + 3]);
        gv.z = __floats2half2_rn(gp[kb + 4], gp[kb + 5]);
        gv.w = __floats2half2_rn(gp[kb + 6], gp[kb + 7]);
        ((H2x4*)gout)[node * 2 + lane2] = gv;
    } else {
        float zp = 0.f;
        #pragma unroll
        for (int q = 0; q < 16; ++q) zp = fmaf(o[q], sWn[jb + q], zp);
        zp += pswap(zp);
        if (lane2 == 0) zout[node] = zp;
    }
}

// last gather: out = z + sum z[src], one thread per node (degree-sorted)
__global__ void k_gz(const float* __restrict__ z, const int* __restrict__ rp,
                     const int* __restrict__ esrc, const int* __restrict__ perm,
                     float* __restrict__ out, int n) {
    int idx = blockIdx.x * blockDim.x + threadIdx.x;
    if (idx >= n) return;
    const int i = perm[idx];
    float acc = z[i];
    int b = rp[i], en = rp[i + 1];
    int j = b;
    for (; j + 4 <= en; j += 4) {
        int s0 = esrc[j], s1 = esrc[j + 1], s2 = esrc[j + 2], s3 = esrc[j + 3];
        float z0 = z[s0], z1 = z[s1], z2 = z[s2], z3 = z[s3];
        acc += (z0 + z1) + (z2 + z3);
    }
    for (; j < en; ++j) acc += z[esrc[j]];
    out[i] = acc;
}

// ---------------------------------------------------------------------------

extern "C" void kernel_launch(void* const* d_in, const int* in_sizes, int n_in,
                              void* d_out, int out_size, void* d_ws, size_t ws_size,
                              hipStream_t stream) {
    const float* x    = (const float*)d_in[0];
    const int*   ei   = (const int*)d_in[1];
    const float* W1_0 = (const float*)d_in[2];
    const float* b1_0 = (const float*)d_in[3];
    const float* W2_0 = (const float*)d_in[4];
    const float* b2_0 = (const float*)d_in[5];
    const float* W1m  = (const float*)d_in[6];
    const float* b1m  = (const float*)d_in[7];
    const float* W2m  = (const float*)d_in[8];
    const float* b2m  = (const float*)d_in[9];
    const float* Wl   = (const float*)d_in[10];

    const int n = in_sizes[0];      // 100000 nodes
    const int e = in_sizes[1] / 2;  // 1.6M edges
    const int* src  = ei;
    const int* dstp = ei + e;
    const int nb = (n + 255) >> 8;

    char* ws = (char*)d_ws;
    size_t off = 0;
    auto alloc = [&](size_t bytes) -> char* {
        char* p = ws + off;
        off += (bytes + 255) & ~size_t(255);
        return p;
    };
    __half2* hP   = (__half2*)alloc((size_t)n * 32 * 2);
    __half2* hQ   = (__half2*)alloc((size_t)n * 32 * 2);
    __half2* gA   = (__half2*)alloc((size_t)n * 16 * 2);
    __half2* gB   = (__half2*)alloc((size_t)n * 16 * 2);
    float*   z    = (float*)alloc((size_t)n * 4);
    int*     rp   = (int*)alloc((size_t)(n + 1) * 4);
    int*     esrc = (int*)alloc((size_t)e * 4);
    uint_t*  pairs= (uint_t*)alloc((size_t)e * 4);
    int*     MT   = (int*)alloc((size_t)NBMAX * NBLK * 4);
    int*     base = (int*)alloc((size_t)(NBMAX + 1) * 4);
    int*     tot  = (int*)alloc((size_t)NBMAX * 4);
    int*     perm = (int*)alloc((size_t)n * 4);
    int*     DH2  = (int*)alloc(64 * 4);
    int*     gcur = (int*)alloc(64 * 4);
    (void)ws_size;

    const int B = 256;
    const int gN = (n + B - 1) / B;
    const int gG = (n + 127) / 128;

    // --- CSR build + degree-sort perm ---
    hipMemsetAsync(DH2, 0, 64 * 4, stream);
    k_hist<<<NBLK, B, 0, stream>>>(dstp, MT, e, nb);
    k_cscan<<<nb, 64, 0, stream>>>(MT, tot, nb);
    k_bscan<<<1, 512, 0, stream>>>(tot, base, rp, nb, e, n);
    k_scatter<<<NBLK, B, 0, stream>>>(src, dstp, MT, base, pairs, e, nb);
    k_build<<<nb, B, 0, stream>>>(pairs, base, rp, esrc, DH2, n);
    k_dbase<<<1, 64, 0, stream>>>(DH2, gcur);
    k_dscatter<<<nb, B, 0, stream>>>(rp, gcur, perm, n);

    // --- block 0 (+ fused g1) ---
    k_b0g<<<gN, B, 0, stream>>>(x, rp, esrc, perm, W1_0, b1_0, W2_0, b2_0,
                                W1m /* W1[0] */, hP, gA, n);

    // --- blocks 1..8, projection fused into epilogue ---
    __half2* A = hP;  __half2* Bf = hQ;
    __half2* gin = gA; __half2* gnx = gB;
    for (int i = 0; i < 8; ++i) {
        if (i < 7) {
            k_gmid<0><<<gG, B, 0, stream>>>(gin, A, rp, esrc, perm,
                                            W2m + i * 512, b1m + i * 16,
                                            b2m + i * 32, W1m + (i + 1) * 512,
                                            Bf, gnx, nullptr, n);
        } else {
            k_gmid<1><<<gG, B, 0, stream>>>(gin, A, rp, esrc, perm,
                                            W2m + i * 512, b1m + i * 16,
                                            b2m + i * 32, Wl,
                                            Bf, nullptr, z, n);
        }
        __half2* t = A; A = Bf; Bf = t;
        __half2* tg = gin; gin = gnx; gnx = tg;
    }

    // --- block 9: gather of z ---
    k_gz<<<gN, B, 0, stream>>>(z, rp, esrc, perm, (float*)d_out, n);
}

// Round 9
// 307.348 us; speedup vs baseline: 1.0896x; 1.0896x over previous
//
#include <hip/hip_runtime.h>
#include <hip/hip_fp16.h>

// ---------------------------------------------------------------------------
// GIN, round 9: degree-sorted FULL RELABEL (fixes round-8's two regressions).
// Nodes renumbered by DESCENDING degree rank: heavy blocks dispatch first
// (no tail), h/g arrays indexed by rank (all non-gather accesses coalesced),
// esrc remapped via inv[] so gathers stay in rank space. Edge order per node
// preserved -> output bit-identical to round 7.
// ---------------------------------------------------------------------------

typedef unsigned int uint_t;

#define NBLK 256
#define NBMAX 400

struct alignas(16) H2x4 { __half2 x, y, z, w; };  // 8 f16 channels

static __device__ __forceinline__ float selu_f(float x) {
    const float scale = 1.0507009873554805f;
    const float alpha = 1.6732632423543772f;
    return x > 0.f ? scale * x : scale * alpha * (__expf(x) - 1.f);
}

static __device__ __forceinline__ int pb0(int v) {   // lanes {0,1}<-0, {2,3}<-2
    return __builtin_amdgcn_mov_dpp(v, 0xA0, 0xf, 0xf, true);
}
static __device__ __forceinline__ int pb1(int v) {   // lanes {0,1}<-1, {2,3}<-3
    return __builtin_amdgcn_mov_dpp(v, 0xF5, 0xf, 0xf, true);
}
static __device__ __forceinline__ float pswap(float x) {  // pair swap [1,0,3,2]
    return __int_as_float(__builtin_amdgcn_mov_dpp(__float_as_int(x), 0xB1, 0xf, 0xf, true));
}

static __device__ __forceinline__ void acc_add(__half2& a0, __half2& a1,
                                               __half2& a2, __half2& a3, H2x4 v) {
    a0 = __hadd2(a0, v.x); a1 = __hadd2(a1, v.y);
    a2 = __hadd2(a2, v.z); a3 = __hadd2(a3, v.w);
}

// ============================ CSR build =====================================

__global__ void k_hist(const int* __restrict__ dst, int* __restrict__ MT,
                       int e, int nb) {
    __shared__ int hist[NBMAX];
    for (int t = threadIdx.x; t < nb; t += 256) hist[t] = 0;
    __syncthreads();
    int chunk = (e + NBLK - 1) / NBLK;
    int lo = blockIdx.x * chunk, hi = min(e, lo + chunk);
    for (int i = lo + threadIdx.x; i < hi; i += 256)
        atomicAdd(&hist[dst[i] >> 8], 1);
    __syncthreads();
    for (int t = threadIdx.x; t < nb; t += 256)
        MT[t * NBLK + blockIdx.x] = hist[t];
}

__global__ void k_cscan(int* __restrict__ MT, int* __restrict__ tot, int nb) {
    int k = blockIdx.x;
    int lane = threadIdx.x;  // 64
    int carry = 0;
    #pragma unroll
    for (int r = 0; r < NBLK; r += 64) {
        int v = MT[k * NBLK + r + lane];
        int inc = v;
        #pragma unroll
        for (int d = 1; d < 64; d <<= 1) {
            int w = __shfl_up(inc, d, 64);
            if (lane >= d) inc += w;
        }
        MT[k * NBLK + r + lane] = carry + inc - v;
        carry += __shfl(inc, 63, 64);
    }
    if (lane == 0) tot[k] = carry;
}

__global__ void k_bscan(const int* __restrict__ tot, int* __restrict__ base,
                        int* __restrict__ rp, int nb, int e, int n) {
    __shared__ int s[512];
    int t = threadIdx.x;
    int v = (t < nb) ? tot[t] : 0;
    s[t] = v;
    __syncthreads();
    #pragma unroll
    for (int d = 1; d < 512; d <<= 1) {
        int w = (t >= d) ? s[t - d] : 0;
        __syncthreads();
        s[t] += w;
        __syncthreads();
    }
    if (t < nb) base[t] = s[t] - v;
    if (t == nb - 1) base[nb] = s[t];
    if (t == 0) rp[n] = e;
}

__global__ void k_scatter(const int* __restrict__ src, const int* __restrict__ dst,
                          const int* __restrict__ MT, const int* __restrict__ base,
                          uint_t* __restrict__ pairs, int e, int nb) {
    __shared__ int cur[NBMAX];
    for (int t = threadIdx.x; t < nb; t += 256)
        cur[t] = base[t] + MT[t * NBLK + blockIdx.x];
    __syncthreads();
    int chunk = (e + NBLK - 1) / NBLK;
    int lo = blockIdx.x * chunk, hi = min(e, lo + chunk);
    for (int i = lo + threadIdx.x; i < hi; i += 256) {
        int d = dst[i];
        int pos = atomicAdd(&cur[d >> 8], 1);
        pairs[pos] = (uint_t)src[i] | ((uint_t)(d & 255) << 24);
    }
}

__global__ void k_build(const uint_t* __restrict__ pairs, const int* __restrict__ base,
                        int* __restrict__ rp, int* __restrict__ esrc,
                        int* __restrict__ DH2, int n) {
    int k = blockIdx.x;
    int bb = base[k], be = base[k + 1];
    __shared__ int cnt[256], cur[256], stmp[256], dh[64];
    int t = threadIdx.x;
    cnt[t] = 0;
    if (t < 64) dh[t] = 0;
    __syncthreads();
    for (int i = bb + t; i < be; i += 256)
        atomicAdd(&cnt[pairs[i] >> 24], 1);
    __syncthreads();
    int v = cnt[t];
    int nd = k * 256 + t;
    if (nd < n) atomicAdd(&dh[min(v, 63)], 1);
    stmp[t] = v;
    __syncthreads();
    #pragma unroll
    for (int d = 1; d < 256; d <<= 1) {
        int w = (t >= d) ? stmp[t - d] : 0;
        __syncthreads();
        stmp[t] += w;
        __syncthreads();
    }
    int excl = stmp[t] - v;
    if (nd < n) rp[nd] = bb + excl;
    cur[t] = bb + excl;
    if (t < 64 && dh[t] > 0) atomicAdd(&DH2[t], dh[t]);
    __syncthreads();
    for (int i = bb + t; i < be; i += 256) {
        uint_t p = pairs[i];
        int pos = atomicAdd(&cur[p >> 24], 1);
        esrc[pos] = (int)(p & 0xFFFFFFu);
    }
}

// DESCENDING exclusive scan of degree histogram: gcur[b] = #nodes with
// bucket > b (heaviest bucket first -> LPT block scheduling).
__global__ void k_dbase(const int* __restrict__ DH2, int* __restrict__ gcur) {
    int lane = threadIdx.x;  // 64
    int b = 63 - lane;
    int v = DH2[b];
    int inc = v;
    #pragma unroll
    for (int d = 1; d < 64; d <<= 1) {
        int w = __shfl_up(inc, d, 64);
        if (lane >= d) inc += w;
    }
    gcur[b] = inc - v;
}

// scatter: rank assignment + inv map + permuted degree + permuted x
__global__ void k_dscatter(const int* __restrict__ rp, int* __restrict__ gcur,
                           int* __restrict__ perm, int* __restrict__ inv,
                           int* __restrict__ deg2, float* __restrict__ x2,
                           const float* __restrict__ x, int n) {
    __shared__ int hist[64], bbase[64], cur2[64];
    int t = threadIdx.x;
    if (t < 64) hist[t] = 0;
    __syncthreads();
    int nd = blockIdx.x * 256 + t;
    int bucket = 0, deg = 0;
    if (nd < n) {
        deg = rp[nd + 1] - rp[nd];
        bucket = min(deg, 63);
        atomicAdd(&hist[bucket], 1);
    }
    __syncthreads();
    if (t < 64 && hist[t] > 0) bbase[t] = atomicAdd(&gcur[t], hist[t]);
    __syncthreads();
    if (t < 64) cur2[t] = (hist[t] > 0) ? bbase[t] : 0;
    __syncthreads();
    if (nd < n) {
        int pos = atomicAdd(&cur2[bucket], 1);
        perm[pos] = nd;
        inv[nd] = pos;
        deg2[pos] = deg;
        x2[pos] = x[nd];
    }
}

// exclusive scan of deg2 -> rp2 (two-level, chunk=1024)
__global__ void k_scan1(const int* __restrict__ cnt, int* __restrict__ rp,
                        int* __restrict__ bsum, int n) {
    int tb = blockIdx.x * 1024 + threadIdx.x * 4;
    int c0 = (tb + 0 < n) ? cnt[tb + 0] : 0;
    int c1 = (tb + 1 < n) ? cnt[tb + 1] : 0;
    int c2 = (tb + 2 < n) ? cnt[tb + 2] : 0;
    int c3 = (tb + 3 < n) ? cnt[tb + 3] : 0;
    int t = c0 + c1 + c2 + c3;
    int lane = threadIdx.x & 63, wave = threadIdx.x >> 6;
    int inc = t;
    #pragma unroll
    for (int d = 1; d < 64; d <<= 1) {
        int v = __shfl_up(inc, d, 64);
        if (lane >= d) inc += v;
    }
    __shared__ int wtot[4];
    if (lane == 63) wtot[wave] = inc;
    __syncthreads();
    int woff = 0;
    #pragma unroll
    for (int w = 0; w < 4; ++w)
        if (w < wave) woff += wtot[w];
    int excl = woff + inc - t;
    if (tb + 0 < n) rp[tb + 0] = excl;
    if (tb + 1 < n) rp[tb + 1] = excl + c0;
    if (tb + 2 < n) rp[tb + 2] = excl + c0 + c1;
    if (tb + 3 < n) rp[tb + 3] = excl + c0 + c1 + c2;
    if (threadIdx.x == 255) bsum[blockIdx.x] = woff + inc;
}

__global__ void k_scan2(int* bsum, int nb) {
    __shared__ int s[256];
    int t = (threadIdx.x < nb) ? bsum[threadIdx.x] : 0;
    s[threadIdx.x] = t;
    __syncthreads();
    #pragma unroll
    for (int d = 1; d < 256; d <<= 1) {
        int v = (threadIdx.x >= (unsigned)d) ? s[threadIdx.x - d] : 0;
        __syncthreads();
        s[threadIdx.x] += v;
        __syncthreads();
    }
    if (threadIdx.x < nb) bsum[threadIdx.x] = s[threadIdx.x] - t;
}

__global__ void k_scan3(int* __restrict__ rp2, const int* __restrict__ bsum,
                        int n, int e) {
    int i = blockIdx.x * blockDim.x + threadIdx.x;
    if (i < n) rp2[i] += bsum[i >> 10];
    if (i == 0) rp2[n] = e;
}

// remap edge lists into rank space (per-node edge order preserved)
__global__ void k_remap(const int* __restrict__ rp, const int* __restrict__ rp2,
                        const int* __restrict__ perm, const int* __restrict__ inv,
                        const int* __restrict__ esrc, int* __restrict__ esrc2, int n) {
    int r = blockIdx.x * 256 + threadIdx.x;
    if (r >= n) return;
    int old = perm[r];
    int bo = rp[old];
    int deg = rp[old + 1] - bo;
    int bn = rp2[r];
    int j = 0;
    for (; j + 4 <= deg; j += 4) {
        int s0 = esrc[bo + j], s1 = esrc[bo + j + 1],
            s2 = esrc[bo + j + 2], s3 = esrc[bo + j + 3];
        esrc2[bn + j]     = inv[s0];
        esrc2[bn + j + 1] = inv[s1];
        esrc2[bn + j + 2] = inv[s2];
        esrc2[bn + j + 3] = inv[s3];
    }
    for (; j < deg; ++j) esrc2[bn + j] = inv[esrc[bo + j]];
}

// ============================ network kernels ===============================
// All node indices below are RANKS (sequential, coalesced).

__global__ void k_b0g(const float* __restrict__ x2, const int* __restrict__ rp,
                      const int* __restrict__ esrc,
                      const float* __restrict__ W1, const float* __restrict__ b1,
                      const float* __restrict__ W2, const float* __restrict__ b2,
                      const float* __restrict__ W1next,
                      __half2* __restrict__ hout, __half2* __restrict__ gout, int n) {
    __shared__ float sW1[16], sb1[16], sW2[512], sb2[32], sWn[512];
    if (threadIdx.x < 16) { sW1[threadIdx.x] = W1[threadIdx.x]; sb1[threadIdx.x] = b1[threadIdx.x]; }
    for (int t = threadIdx.x; t < 512; t += 256) { sW2[t] = W2[t]; sWn[t] = W1next[t]; }
    if (threadIdx.x < 32) sb2[threadIdx.x] = b2[threadIdx.x];
    __syncthreads();
    int i = blockIdx.x * blockDim.x + threadIdx.x;
    if (i >= n) return;
    float a = x2[i];
    int b = rp[i], en = rp[i + 1];
    int j = b;
    for (; j + 4 <= en; j += 4) {
        int s0 = esrc[j], s1 = esrc[j + 1], s2 = esrc[j + 2], s3 = esrc[j + 3];
        float v0 = x2[s0], v1 = x2[s1], v2 = x2[s2], v3 = x2[s3];
        a += (v0 + v1) + (v2 + v3);
    }
    for (; j < en; ++j) a += x2[esrc[j]];
    float u[16];
    #pragma unroll
    for (int k = 0; k < 16; ++k) u[k] = selu_f(fmaf(a, sW1[k], sb1[k]));
    float row[32];
    #pragma unroll
    for (int jj = 0; jj < 32; ++jj) {
        float acc = sb2[jj];
        #pragma unroll
        for (int k = 0; k < 16; ++k) acc = fmaf(u[k], sW2[k * 32 + jj], acc);
        row[jj] = acc;
    }
    H2x4* op = (H2x4*)hout + i * 4;
    #pragma unroll
    for (int q = 0; q < 4; ++q) {
        H2x4 vv;
        vv.x = __floats2half2_rn(row[q * 8 + 0], row[q * 8 + 1]);
        vv.y = __floats2half2_rn(row[q * 8 + 2], row[q * 8 + 3]);
        vv.z = __floats2half2_rn(row[q * 8 + 4], row[q * 8 + 5]);
        vv.w = __floats2half2_rn(row[q * 8 + 6], row[q * 8 + 7]);
        op[q] = vv;
    }
    float g[16];
    #pragma unroll
    for (int k = 0; k < 16; ++k) g[k] = 0.f;
    #pragma unroll
    for (int c = 0; c < 32; ++c) {
        float vc = row[c];
        #pragma unroll
        for (int k = 0; k < 16; ++k) g[k] = fmaf(vc, sWn[c * 16 + k], g[k]);
    }
    H2x4* gp = (H2x4*)gout + i * 2;
    #pragma unroll
    for (int q = 0; q < 2; ++q) {
        H2x4 vv;
        vv.x = __floats2half2_rn(g[q * 8 + 0], g[q * 8 + 1]);
        vv.y = __floats2half2_rn(g[q * 8 + 2], g[q * 8 + 3]);
        vv.z = __floats2half2_rn(g[q * 8 + 4], g[q * 8 + 5]);
        vv.w = __floats2half2_rn(g[q * 8 + 6], g[q * 8 + 7]);
        gp[q] = vv;
    }
}

template<int MODE>
__global__ __launch_bounds__(256, 4) void k_gmid(
    const __half2* __restrict__ gin, const __half2* __restrict__ hin,
    const int* __restrict__ rp, const int* __restrict__ esrc,
    const float* __restrict__ W2, const float* __restrict__ b1,
    const float* __restrict__ b2, const float* __restrict__ Wnext,
    __half2* __restrict__ hout, __half2* __restrict__ gout,
    float* __restrict__ zout, int n) {
    __shared__ float sW2[512], sb1[16], sb2[32];
    __shared__ float sWn[512];
    for (int t = threadIdx.x; t < 512; t += 256) sW2[t] = W2[t];
    if (MODE == 0) {
        for (int t = threadIdx.x; t < 512; t += 256) sWn[t] = Wnext[t];
    } else {
        if (threadIdx.x < 32) sWn[threadIdx.x] = Wnext[threadIdx.x];
    }
    if (threadIdx.x < 16) sb1[threadIdx.x] = b1[threadIdx.x];
    else if (threadIdx.x < 48) sb2[threadIdx.x - 16] = b2[threadIdx.x - 16];
    __syncthreads();

    const int lane2 = threadIdx.x & 1;
    const int node = blockIdx.x * 128 + (threadIdx.x >> 1);
    if (node >= n) return;

    const H2x4* grows = (const H2x4*)gin;
    H2x4 a = grows[node * 2 + lane2];
    __half2 a0 = a.x, a1 = a.y, a2 = a.z, a3 = a.w;

    int b = rp[node];
    int deg = rp[node + 1] - b;
    int j0 = 0;
    for (; j0 + 8 <= deg; j0 += 8) {
        int e0 = esrc[b + j0 + lane2];
        int e1 = esrc[b + j0 + 2 + lane2];
        int e2 = esrc[b + j0 + 4 + lane2];
        int e3 = esrc[b + j0 + 6 + lane2];
        int s0 = pb0(e0), s1 = pb1(e0), s2 = pb0(e1), s3 = pb1(e1);
        int s4 = pb0(e2), s5 = pb1(e2), s6 = pb0(e3), s7 = pb1(e3);
        H2x4 v0 = grows[s0 * 2 + lane2];
        H2x4 v1 = grows[s1 * 2 + lane2];
        H2x4 v2 = grows[s2 * 2 + lane2];
        H2x4 v3 = grows[s3 * 2 + lane2];
        H2x4 v4 = grows[s4 * 2 + lane2];
        H2x4 v5 = grows[s5 * 2 + lane2];
        H2x4 v6 = grows[s6 * 2 + lane2];
        H2x4 v7 = grows[s7 * 2 + lane2];
        acc_add(a0, a1, a2, a3, v0);
        acc_add(a0, a1, a2, a3, v1);
        acc_add(a0, a1, a2, a3, v2);
        acc_add(a0, a1, a2, a3, v3);
        acc_add(a0, a1, a2, a3, v4);
        acc_add(a0, a1, a2, a3, v5);
        acc_add(a0, a1, a2, a3, v6);
        acc_add(a0, a1, a2, a3, v7);
    }
    for (; j0 < deg; ++j0) {
        int s = esrc[b + j0];
        H2x4 v = grows[s * 2 + lane2];
        acc_add(a0, a1, a2, a3, v);
    }

    float2 f0 = __half22float2(a0), f1 = __half22float2(a1),
           f2 = __half22float2(a2), f3 = __half22float2(a3);
    float u[8] = {f0.x, f0.y, f1.x, f1.y, f2.x, f2.y, f3.x, f3.y};
    const int kb = lane2 * 8;
    #pragma unroll
    for (int q = 0; q < 8; ++q) u[q] = selu_f(u[q] + sb1[kb + q]);

    float ua[16];
    #pragma unroll
    for (int q = 0; q < 8; ++q) {
        float uo = pswap(u[q]);
        ua[q]     = lane2 ? uo   : u[q];
        ua[8 + q] = lane2 ? u[q] : uo;
    }

    const H2x4* hrows = (const H2x4*)hin;
    H2x4 h0 = hrows[node * 4 + lane2 * 2];
    H2x4 h1 = hrows[node * 4 + lane2 * 2 + 1];
    float hv[16];
    {
        float2 g0 = __half22float2(h0.x), g1 = __half22float2(h0.y),
               g2 = __half22float2(h0.z), g3 = __half22float2(h0.w);
        float2 g4 = __half22float2(h1.x), g5 = __half22float2(h1.y),
               g6 = __half22float2(h1.z), g7 = __half22float2(h1.w);
        hv[0] = g0.x; hv[1] = g0.y; hv[2] = g1.x; hv[3] = g1.y;
        hv[4] = g2.x; hv[5] = g2.y; hv[6] = g3.x; hv[7] = g3.y;
        hv[8] = g4.x; hv[9] = g4.y; hv[10] = g5.x; hv[11] = g5.y;
        hv[12] = g6.x; hv[13] = g6.y; hv[14] = g7.x; hv[15] = g7.y;
    }

    const int jb = lane2 * 16;
    float o[16];
    #pragma unroll
    for (int q = 0; q < 16; ++q) {
        float oo = sb2[jb + q];
        #pragma unroll
        for (int k = 0; k < 16; ++k) oo = fmaf(ua[k], sW2[k * 32 + jb + q], oo);
        o[q] = oo + hv[q];
    }

    if (MODE == 0) {
        H2x4 o0, o1;
        o0.x = __floats2half2_rn(o[0], o[1]);   o0.y = __floats2half2_rn(o[2], o[3]);
        o0.z = __floats2half2_rn(o[4], o[5]);   o0.w = __floats2half2_rn(o[6], o[7]);
        o1.x = __floats2half2_rn(o[8], o[9]);   o1.y = __floats2half2_rn(o[10], o[11]);
        o1.z = __floats2half2_rn(o[12], o[13]); o1.w = __floats2half2_rn(o[14], o[15]);
        ((H2x4*)hout)[node * 4 + lane2 * 2]     = o0;
        ((H2x4*)hout)[node * 4 + lane2 * 2 + 1] = o1;
        float gp[16];
        #pragma unroll
        for (int k = 0; k < 16; ++k) gp[k] = 0.f;
        #pragma unroll
        for (int q = 0; q < 16; ++q) {
            float vc = o[q];
            #pragma unroll
            for (int k = 0; k < 16; ++k)
                gp[k] = fmaf(vc, sWn[(jb + q) * 16 + k], gp[k]);
        }
        #pragma unroll
        for (int k = 0; k < 16; ++k) gp[k] += pswap(gp[k]);
        H2x4 gv;
        gv.x = __floats2half2_rn(gp[kb + 0], gp[kb + 1]);
        gv.y = __floats2half2_rn(gp[kb + 2], gp[kb + 3]);
        gv.z = __floats2half2_rn(gp[kb + 4], gp[kb + 5]);
        gv.w = __floats2half2_rn(gp[kb + 6], gp[kb + 7]);
        ((H2x4*)gout)[node * 2 + lane2] = gv;
    } else {
        float zp = 0.f;
        #pragma unroll
        for (int q = 0; q < 16; ++q) zp = fmaf(o[q], sWn[jb + q], zp);
        zp += pswap(zp);
        if (lane2 == 0) zout[node] = zp;
    }
}

// last gather: out[perm[rank]] = z[rank] + sum z[esrc2[...]]
__global__ void k_gz(const float* __restrict__ z, const int* __restrict__ rp,
                     const int* __restrict__ esrc, const int* __restrict__ perm,
                     float* __restrict__ out, int n) {
    int i = blockIdx.x * blockDim.x + threadIdx.x;
    if (i >= n) return;
    float acc = z[i];
    int b = rp[i], en = rp[i + 1];
    int j = b;
    for (; j + 4 <= en; j += 4) {
        int s0 = esrc[j], s1 = esrc[j + 1], s2 = esrc[j + 2], s3 = esrc[j + 3];
        float z0 = z[s0], z1 = z[s1], z2 = z[s2], z3 = z[s3];
        acc += (z0 + z1) + (z2 + z3);
    }
    for (; j < en; ++j) acc += z[esrc[j]];
    out[perm[i]] = acc;
}

// ---------------------------------------------------------------------------

extern "C" void kernel_launch(void* const* d_in, const int* in_sizes, int n_in,
                              void* d_out, int out_size, void* d_ws, size_t ws_size,
                              hipStream_t stream) {
    const float* x    = (const float*)d_in[0];
    const int*   ei   = (const int*)d_in[1];
    const float* W1_0 = (const float*)d_in[2];
    const float* b1_0 = (const float*)d_in[3];
    const float* W2_0 = (const float*)d_in[4];
    const float* b2_0 = (const float*)d_in[5];
    const float* W1m  = (const float*)d_in[6];
    const float* b1m  = (const float*)d_in[7];
    const float* W2m  = (const float*)d_in[8];
    const float* b2m  = (const float*)d_in[9];
    const float* Wl   = (const float*)d_in[10];

    const int n = in_sizes[0];      // 100000 nodes
    const int e = in_sizes[1] / 2;  // 1.6M edges
    const int* src  = ei;
    const int* dstp = ei + e;
    const int nb = (n + 255) >> 8;       // dst buckets (391)
    const int nb2 = (n + 1023) / 1024;   // scan chunks (98)

    char* ws = (char*)d_ws;
    size_t off = 0;
    auto alloc = [&](size_t bytes) -> char* {
        char* p = ws + off;
        off += (bytes + 255) & ~size_t(255);
        return p;
    };
    __half2* hP    = (__half2*)alloc((size_t)n * 32 * 2);
    __half2* hQ    = (__half2*)alloc((size_t)n * 32 * 2);
    __half2* gA    = (__half2*)alloc((size_t)n * 16 * 2);
    __half2* gB    = (__half2*)alloc((size_t)n * 16 * 2);
    float*   z     = (float*)alloc((size_t)n * 4);
    float*   x2    = (float*)alloc((size_t)n * 4);
    int*     rp    = (int*)alloc((size_t)(n + 1) * 4);
    int*     rp2   = (int*)alloc((size_t)(n + 1) * 4);
    int*     esrc  = (int*)alloc((size_t)e * 4);
    int*     esrc2 = (int*)alloc((size_t)e * 4);
    uint_t*  pairs = (uint_t*)alloc((size_t)e * 4);
    int*     MT    = (int*)alloc((size_t)NBMAX * NBLK * 4);
    int*     base  = (int*)alloc((size_t)(NBMAX + 1) * 4);
    int*     tot   = (int*)alloc((size_t)NBMAX * 4);
    int*     perm  = (int*)alloc((size_t)n * 4);
    int*     inv   = (int*)alloc((size_t)n * 4);
    int*     deg2  = (int*)alloc((size_t)n * 4);
    int*     DH2   = (int*)alloc(64 * 4);
    int*     gcur  = (int*)alloc(64 * 4);
    int*     bsum2 = (int*)alloc(4096);
    (void)ws_size;

    const int B = 256;
    const int gN = (n + B - 1) / B;
    const int gG = (n + 127) / 128;

    // --- CSR build + descending-degree relabel ---
    hipMemsetAsync(DH2, 0, 64 * 4, stream);
    k_hist<<<NBLK, B, 0, stream>>>(dstp, MT, e, nb);
    k_cscan<<<nb, 64, 0, stream>>>(MT, tot, nb);
    k_bscan<<<1, 512, 0, stream>>>(tot, base, rp, nb, e, n);
    k_scatter<<<NBLK, B, 0, stream>>>(src, dstp, MT, base, pairs, e, nb);
    k_build<<<nb, B, 0, stream>>>(pairs, base, rp, esrc, DH2, n);
    k_dbase<<<1, 64, 0, stream>>>(DH2, gcur);
    k_dscatter<<<gN, B, 0, stream>>>(rp, gcur, perm, inv, deg2, x2, x, n);
    k_scan1<<<nb2, B, 0, stream>>>(deg2, rp2, bsum2, n);
    k_scan2<<<1, 256, 0, stream>>>(bsum2, nb2);
    k_scan3<<<gN, B, 0, stream>>>(rp2, bsum2, n, e);
    k_remap<<<gN, B, 0, stream>>>(rp, rp2, perm, inv, esrc, esrc2, n);

    // --- block 0 (+ fused g1), rank space ---
    k_b0g<<<gN, B, 0, stream>>>(x2, rp2, esrc2, W1_0, b1_0, W2_0, b2_0,
                                W1m, hP, gA, n);

    // --- blocks 1..8 ---
    __half2* A = hP;  __half2* Bf = hQ;
    __half2* gin = gA; __half2* gnx = gB;
    for (int i = 0; i < 8; ++i) {
        if (i < 7) {
            k_gmid<0><<<gG, B, 0, stream>>>(gin, A, rp2, esrc2,
                                            W2m + i * 512, b1m + i * 16,
                                            b2m + i * 32, W1m + (i + 1) * 512,
                                            Bf, gnx, nullptr, n);
        } else {
            k_gmid<1><<<gG, B, 0, stream>>>(gin, A, rp2, esrc2,
                                            W2m + i * 512, b1m + i * 16,
                                            b2m + i * 32, Wl,
                                            Bf, nullptr, z, n);
        }
        __half2* t = A; A = Bf; Bf = t;
        __half2* tg = gin; gin = gnx; gnx = tg;
    }

    // --- block 9: gather of z, scatter to original ids ---
    k_gz<<<gN, B, 0, stream>>>(z, rp2, esrc2, perm, (float*)d_out, n);
}